// Round 32
// baseline (47.087 us; speedup 1.0000x reference)
//
#include <hip/hip_runtime.h>

// ---------------------------------------------------------------------------
// FFT_Conv_Layer == 3x3 "same" spatial conv with flipped REAL filter plane.
//
// Ladder: R25 18.53 (champion) | R27 diag: [acc+K+store] marginal = 3.47us
// => S(stage) + F(ramp/drain) = 15.07us | R28 19.55: decode removal FAILED
// -> phase A is LATENCY-bound, not issue-bound (decode hid under loads).
// R32 DIAGNOSTIC: repeat phase A (pads+image+wf gather) 4x on R25 champion,
// K+store once. dur = F + 4S + 3.47, combined with S+F=15.07 solves S and F.
//   dur >= ~48 -> S >= 10: staging dominates -> vectorize (dwordx4) next.
//   dur ~ 33-40 -> F ~ 8-10: fixed ramp/drain -> near practical floor.
// CSE guard: per-rep opaque zero offset on imgs/filts pointers (asm volatile)
// so the compiler cannot reuse rep-1 load results; staging is idempotent.
// ---------------------------------------------------------------------------

typedef _Float16 f16x8 __attribute__((ext_vector_type(8)));
typedef float    f32x4 __attribute__((ext_vector_type(4)));

#define NB 16
#define NC 64
#define NH 64
#define NW 64
#define CHUNKS 528                 // 66 xp positions * 8 channel-chunks per slab
#define SLAB_BYTES (CHUNKS * 16)   // 8448 B per image row slab
#define IMG_LDS (6 * SLAB_BYTES)   // 50,688 B
#define WF_HALFS (9 * 2 * 4 * 64 * 8)  // 36,864 halfs = 73,728 B = 4608 chunks
#define SREPS 4

__global__ __launch_bounds__(512, 1) void conv_one(const float* __restrict__ imgs,
                                                   const float* __restrict__ filts,
                                                   float* __restrict__ out) {
    __shared__ char lds[IMG_LDS + WF_HALFS * 2];   // 124,416 B
    char* wfl = lds + IMG_LDS;
    const int bid = blockIdx.x;
    const int swz = ((bid & 7) << 5) | (bid >> 3);   // bijective: 256 = 8*32
    const int b   = swz >> 4;
    const int y0  = (swz & 15) << 2;     // first of 4 output rows
    const int tid = threadIdx.x;
    const int w   = tid >> 6;            // wave 0..7
    const int l   = tid & 63;
    const int h   = l >> 4;              // k-chunk lane group
    const int r   = l & 15;              // A-row / B-col within fragment

    int zero = 0;
    asm volatile("" : "+v"(zero));       // opaque 0: defeats cross-rep load CSE

    #pragma unroll 1
    for (int rep = 0; rep < SREPS; ++rep) {
        const float* imgs_r  = imgs  + (size_t)(rep * zero);
        const float* filts_r = filts + (size_t)(rep * zero);

        // ---- pads: 6 slabs x 16 chunks (xp = 0, 65) ----
        if (tid < 96) {
            const int sl  = tid >> 4;
            const int rem = tid & 15;
            const int ci  = rem >> 1;
            const int xp2 = (rem & 1) ? 65 : 0;
            const int c2  = xp2 * 8 + (ci ^ (xp2 & 7));
            f16x8 z;
            #pragma unroll
            for (int k = 0; k < 8; ++k) z[k] = (_Float16)0.f;
            *reinterpret_cast<f16x8*>(lds + sl * SLAB_BYTES + c2 * 16) = z;
        }

        // ---- image: stage 6 slabs (rows y0-1..y0+4), 48 jobs over 8 waves --
        #pragma unroll
        for (int j = 0; j < 6; ++j) {
            const int job = w + j * 8;
            const int sl  = job >> 3;
            const int ci  = job & 7;
            const int yy  = y0 - 1 + sl;
            float fr[8];
            if ((unsigned)yy < (unsigned)NH) {
                const float* src = imgs_r + (((size_t)(b * NC + ci * 8)) * NH + yy) * NW + l;
                #pragma unroll
                for (int k = 0; k < 8; ++k) fr[k] = src[(size_t)k * NH * NW];
            } else {
                #pragma unroll
                for (int k = 0; k < 8; ++k) fr[k] = 0.f;
            }
            f16x8 v;
            #pragma unroll
            for (int k = 0; k < 8; ++k) v[k] = (_Float16)fr[k];
            const int xp = l + 1;
            const int chunk = xp * 8 + (ci ^ (xp & 7));
            *reinterpret_cast<f16x8*>(lds + sl * SLAB_BYTES + chunk * 16) = v;
        }

        // ---- wf: coalesced gather + LDS scatter (72 entries/thread) ----
        {
            const float2* filts2 = reinterpret_cast<const float2*>(filts_r);
            _Float16* wfh = reinterpret_cast<_Float16*>(wfl);
            #pragma unroll
            for (int k = 0; k < 72; ++k) {
                const int f = tid + k * 512;         // entry = i*576 + o*9 + t
                const float v = filts2[f].x;         // real plane
                const int i   = f / 576;
                const int rem = f - i * 576;
                const int o   = rem / 9;
                const int t   = rem - o * 9;
                const int kc = i >> 5, hh = (i >> 3) & 3, e = i & 7;
                const int n  = o >> 4,  rr = o & 15;
                const int c  = ((t * 2 + kc) * 4 + n) * 64 + hh * 16 + rr;
                wfh[c * 8 + e] = (_Float16)v;
            }
        }
        __syncthreads();
    }

    const int row = w >> 1;              // output row within quad (0..3)
    const int xh  = w & 1;               // x half (0..1)

    f32x4 acc[2][4];
    #pragma unroll
    for (int m = 0; m < 2; ++m)
        #pragma unroll
        for (int n = 0; n < 4; ++n)
            acc[m][n] = f32x4{0.f, 0.f, 0.f, 0.f};

    #pragma unroll
    for (int ky = 0; ky < 3; ++ky) {
        const char* slab = lds + (row + 2 - ky) * SLAB_BYTES;   // sl in 0..5
        #pragma unroll
        for (int kx = 0; kx < 3; ++kx) {
            const int t = ky * 3 + kx;
            const char* wt = wfl + (size_t)t * 8192;   // 512 chunks * 16B per tap
            #pragma unroll
            for (int kc = 0; kc < 2; ++kc) {
                f16x8 a[2], bb[4];
                #pragma unroll
                for (int m = 0; m < 2; ++m) {
                    const int xp = xh * 32 + m * 16 + r + 2 - kx;  // 0..65
                    const int chunk = xp * 8 + (((kc << 2) + h) ^ (xp & 7));
                    a[m] = *reinterpret_cast<const f16x8*>(slab + chunk * 16);
                }
                #pragma unroll
                for (int n = 0; n < 4; ++n)
                    bb[n] = *reinterpret_cast<const f16x8*>(
                        wt + (size_t)(kc * 4 + n) * 1024 + l * 16);
                #pragma unroll
                for (int m = 0; m < 2; ++m)
                    #pragma unroll
                    for (int n = 0; n < 4; ++n)
                        acc[m][n] = __builtin_amdgcn_mfma_f32_16x16x32_f16(a[m], bb[n], acc[m][n], 0, 0, 0);
            }
        }
    }

    const int y = y0 + row;
    #pragma unroll
    for (int m = 0; m < 2; ++m) {
        const int x0 = xh * 32 + m * 16 + h * 4;
        #pragma unroll
        for (int n = 0; n < 4; ++n) {
            const int o = n * 16 + r;
            *reinterpret_cast<f32x4*>(out + (((size_t)(b * 64 + o) * 64 + y) * 64) + x0) = acc[m][n];
        }
    }
}

extern "C" void kernel_launch(void* const* d_in, const int* in_sizes, int n_in,
                              void* d_out, int out_size, void* d_ws, size_t ws_size,
                              hipStream_t stream) {
    const float* imgs  = (const float*)d_in[0];   // [16][64][64][64] f32
    const float* filts = (const float*)d_in[1];   // [1][64][64][3][3][2] f32
    float* out = (float*)d_out;                   // [16][64][64][64] f32
    (void)d_ws; (void)ws_size;                    // no workspace needed

    hipLaunchKernelGGL(conv_one, dim3(256), dim3(512), 0, stream, imgs, filts, out);
}

// Round 33
// 18.821 us; speedup vs baseline: 2.5018x; 2.5018x over previous
//
#include <hip/hip_runtime.h>

// ---------------------------------------------------------------------------
// FFT_Conv_Layer == 3x3 "same" spatial conv with flipped REAL filter plane.
//
// Ladder: R25 18.53 (champion) | R27: [acc+K+store] = 3.47us | R32: S(stage)
// = 9.5us, F(fixed) = 5.6us. Staging is LATENCY-BATCHED: per-job
// {8 loads -> vmcnt -> cvt -> ds_write} = ~6 serial latency windows.
// R33 (T14 async-split, single lever vs R25): issue ALL 48 image loads into
// registers first; run the whole wf gather (72 coalesced loads + decode +
// scatter, ~2us of work) UNDER the image-load latency; then pads; then image
// cvt + 6 conflict-free ds_write_b128. K-loop / stores / layout unchanged.
// ---------------------------------------------------------------------------

typedef _Float16 f16x8 __attribute__((ext_vector_type(8)));
typedef float    f32x4 __attribute__((ext_vector_type(4)));

#define NB 16
#define NC 64
#define NH 64
#define NW 64
#define CHUNKS 528                 // 66 xp positions * 8 channel-chunks per slab
#define SLAB_BYTES (CHUNKS * 16)   // 8448 B per image row slab
#define IMG_LDS (6 * SLAB_BYTES)   // 50,688 B
#define WF_HALFS (9 * 2 * 4 * 64 * 8)  // 36,864 halfs = 73,728 B = 4608 chunks

__global__ __launch_bounds__(512, 1) void conv_one(const float* __restrict__ imgs,
                                                   const float* __restrict__ filts,
                                                   float* __restrict__ out) {
    __shared__ char lds[IMG_LDS + WF_HALFS * 2];   // 124,416 B
    char* wfl = lds + IMG_LDS;
    const int bid = blockIdx.x;
    const int swz = ((bid & 7) << 5) | (bid >> 3);   // bijective: 256 = 8*32
    const int b   = swz >> 4;
    const int y0  = (swz & 15) << 2;     // first of 4 output rows
    const int tid = threadIdx.x;
    const int w   = tid >> 6;            // wave 0..7
    const int l   = tid & 63;
    const int h   = l >> 4;              // k-chunk lane group
    const int r   = l & 15;              // A-row / B-col within fragment

    // ---- (1) issue ALL 48 image loads into registers (one latency window) --
    float fr[6][8];
    #pragma unroll
    for (int j = 0; j < 6; ++j) {
        const int job = w + j * 8;
        const int sl  = job >> 3;        // slab 0..5
        const int ci  = job & 7;         // channel chunk
        const int yy  = y0 - 1 + sl;
        if ((unsigned)yy < (unsigned)NH) {
            const float* src = imgs + (((size_t)(b * NC + ci * 8)) * NH + yy) * NW + l;
            #pragma unroll
            for (int k = 0; k < 8; ++k) fr[j][k] = src[(size_t)k * NH * NW];
        } else {
            #pragma unroll
            for (int k = 0; k < 8; ++k) fr[j][k] = 0.f;
        }
    }

    // ---- (2) wf gather runs UNDER the image-load latency ----
    {
        const float2* filts2 = reinterpret_cast<const float2*>(filts);
        _Float16* wfh = reinterpret_cast<_Float16*>(wfl);
        #pragma unroll
        for (int k = 0; k < 72; ++k) {
            const int f = tid + k * 512;         // entry = i*576 + o*9 + t
            const float v = filts2[f].x;         // real plane
            const int i   = f / 576;
            const int rem = f - i * 576;
            const int o   = rem / 9;
            const int t   = rem - o * 9;
            const int kc = i >> 5, hh = (i >> 3) & 3, e = i & 7;
            const int n  = o >> 4,  rr = o & 15;
            const int c  = ((t * 2 + kc) * 4 + n) * 64 + hh * 16 + rr;
            wfh[c * 8 + e] = (_Float16)v;
        }
    }

    // ---- (3) pads: 6 slabs x 16 chunks (xp = 0, 65) ----
    if (tid < 96) {
        const int sl  = tid >> 4;
        const int rem = tid & 15;
        const int ci  = rem >> 1;
        const int xp2 = (rem & 1) ? 65 : 0;
        const int c2  = xp2 * 8 + (ci ^ (xp2 & 7));
        f16x8 z;
        #pragma unroll
        for (int k = 0; k < 8; ++k) z[k] = (_Float16)0.f;
        *reinterpret_cast<f16x8*>(lds + sl * SLAB_BYTES + c2 * 16) = z;
    }

    // ---- (4) image cvt + 6 conflict-free swizzled ds_write_b128 ----
    #pragma unroll
    for (int j = 0; j < 6; ++j) {
        const int job = w + j * 8;
        const int sl  = job >> 3;
        const int ci  = job & 7;
        f16x8 v;
        #pragma unroll
        for (int k = 0; k < 8; ++k) v[k] = (_Float16)fr[j][k];
        const int xp = l + 1;
        const int chunk = xp * 8 + (ci ^ (xp & 7));
        *reinterpret_cast<f16x8*>(lds + sl * SLAB_BYTES + chunk * 16) = v;
    }
    __syncthreads();

    const int row = w >> 1;              // output row within quad (0..3)
    const int xh  = w & 1;               // x half (0..1)

    f32x4 acc[2][4];
    #pragma unroll
    for (int m = 0; m < 2; ++m)
        #pragma unroll
        for (int n = 0; n < 4; ++n)
            acc[m][n] = f32x4{0.f, 0.f, 0.f, 0.f};

    #pragma unroll
    for (int ky = 0; ky < 3; ++ky) {
        const char* slab = lds + (row + 2 - ky) * SLAB_BYTES;   // sl in 0..5
        #pragma unroll
        for (int kx = 0; kx < 3; ++kx) {
            const int t = ky * 3 + kx;
            const char* wt = wfl + (size_t)t * 8192;   // 512 chunks * 16B per tap
            #pragma unroll
            for (int kc = 0; kc < 2; ++kc) {
                f16x8 a[2], bb[4];
                #pragma unroll
                for (int m = 0; m < 2; ++m) {
                    const int xp = xh * 32 + m * 16 + r + 2 - kx;  // 0..65
                    const int chunk = xp * 8 + (((kc << 2) + h) ^ (xp & 7));
                    a[m] = *reinterpret_cast<const f16x8*>(slab + chunk * 16);
                }
                #pragma unroll
                for (int n = 0; n < 4; ++n)
                    bb[n] = *reinterpret_cast<const f16x8*>(
                        wt + (size_t)(kc * 4 + n) * 1024 + l * 16);
                #pragma unroll
                for (int m = 0; m < 2; ++m)
                    #pragma unroll
                    for (int n = 0; n < 4; ++n)
                        acc[m][n] = __builtin_amdgcn_mfma_f32_16x16x32_f16(a[m], bb[n], acc[m][n], 0, 0, 0);
            }
        }
    }

    const int y = y0 + row;
    #pragma unroll
    for (int m = 0; m < 2; ++m) {
        const int x0 = xh * 32 + m * 16 + h * 4;
        #pragma unroll
        for (int n = 0; n < 4; ++n) {
            const int o = n * 16 + r;
            *reinterpret_cast<f32x4*>(out + (((size_t)(b * 64 + o) * 64 + y) * 64) + x0) = acc[m][n];
        }
    }
}

extern "C" void kernel_launch(void* const* d_in, const int* in_sizes, int n_in,
                              void* d_out, int out_size, void* d_ws, size_t ws_size,
                              hipStream_t stream) {
    const float* imgs  = (const float*)d_in[0];   // [16][64][64][64] f32
    const float* filts = (const float*)d_in[1];   // [1][64][64][3][3][2] f32
    float* out = (float*)d_out;                   // [16][64][64][64] f32
    (void)d_ws; (void)ws_size;                    // no workspace needed

    hipLaunchKernelGGL(conv_one, dim3(256), dim3(512), 0, stream, imgs, filts, out);
}

// Round 34
// 18.349 us; speedup vs baseline: 2.5662x; 1.0257x over previous
//
#include <hip/hip_runtime.h>

// ---------------------------------------------------------------------------
// FFT_Conv_Layer == 3x3 "same" spatial conv with flipped REAL filter plane:
//   out[b,o,y,x] = sum_{i,ky,kx} filts[0,i,o,ky,kx,0] * img[b,i,y+1-ky,x+1-kx]
// (imag filter plane only reaches the imaginary output, dropped by .real;
//  circular conv at S=66 == full linear conv; crop [1:-1] => "same" conv.)
//
// FINAL = R25 champion (18.53us, vs 22.5 baseline):
//   - single dispatch, no workspace
//   - 256 blocks (XCD-swizzled bijectively) = (b, 4-row quad), 8 waves
//   - LDS 124,416B: image 6 slabs (XOR-swizzled chunks, conflict-free b128)
//     + full weight-fragment buffer
//   - wf gather: coalesced float2 reads of filts (L2-resident), decode,
//     scatter to LDS fragment layout — overlapped with image staging
//   - wave tile 32x x 64o (2m x 4n 16x16x32 f16 MFMA frags), A+B from LDS
//   - C/D layout (m89/m91): o = n*16+(lane&15), x = m*16+(lane>>4)*4+j
// Session evidence: stage 9.5us + fixed 5.6us + K/store 3.5us; launch
// overhead ~0 (R24); issue-order, TLP, traffic, pipelining levers all
// neutral (R6-R33) — latency/phase-structure floor for this decomposition.
// ---------------------------------------------------------------------------

typedef _Float16 f16x8 __attribute__((ext_vector_type(8)));
typedef float    f32x4 __attribute__((ext_vector_type(4)));

#define NB 16
#define NC 64
#define NH 64
#define NW 64
#define CHUNKS 528                 // 66 xp positions * 8 channel-chunks per slab
#define SLAB_BYTES (CHUNKS * 16)   // 8448 B per image row slab
#define IMG_LDS (6 * SLAB_BYTES)   // 50,688 B
#define WF_HALFS (9 * 2 * 4 * 64 * 8)  // 36,864 halfs = 73,728 B = 4608 chunks

__global__ __launch_bounds__(512, 1) void conv_one(const float* __restrict__ imgs,
                                                   const float* __restrict__ filts,
                                                   float* __restrict__ out) {
    __shared__ char lds[IMG_LDS + WF_HALFS * 2];   // 124,416 B
    char* wfl = lds + IMG_LDS;
    const int bid = blockIdx.x;
    const int swz = ((bid & 7) << 5) | (bid >> 3);   // bijective: 256 = 8*32
    const int b   = swz >> 4;
    const int y0  = (swz & 15) << 2;     // first of 4 output rows
    const int tid = threadIdx.x;
    const int w   = tid >> 6;            // wave 0..7
    const int l   = tid & 63;
    const int h   = l >> 4;              // k-chunk lane group
    const int r   = l & 15;              // A-row / B-col within fragment

    // ---- pads: 6 slabs x 16 chunks (xp = 0, 65) ----
    if (tid < 96) {
        const int sl  = tid >> 4;
        const int rem = tid & 15;
        const int ci  = rem >> 1;
        const int xp2 = (rem & 1) ? 65 : 0;
        const int c2  = xp2 * 8 + (ci ^ (xp2 & 7));
        f16x8 z;
        #pragma unroll
        for (int k = 0; k < 8; ++k) z[k] = (_Float16)0.f;
        *reinterpret_cast<f16x8*>(lds + sl * SLAB_BYTES + c2 * 16) = z;
    }

    // ---- image: stage 6 slabs (rows y0-1 .. y0+4), 48 jobs over 8 waves ----
    #pragma unroll
    for (int j = 0; j < 6; ++j) {
        const int job = w + j * 8;
        const int sl  = job >> 3;
        const int ci  = job & 7;
        const int yy  = y0 - 1 + sl;
        float fr[8];
        if ((unsigned)yy < (unsigned)NH) {
            const float* src = imgs + (((size_t)(b * NC + ci * 8)) * NH + yy) * NW + l;
            #pragma unroll
            for (int k = 0; k < 8; ++k) fr[k] = src[(size_t)k * NH * NW];
        } else {
            #pragma unroll
            for (int k = 0; k < 8; ++k) fr[k] = 0.f;
        }
        f16x8 v;
        #pragma unroll
        for (int k = 0; k < 8; ++k) v[k] = (_Float16)fr[k];
        const int xp = l + 1;
        const int chunk = xp * 8 + (ci ^ (xp & 7));
        *reinterpret_cast<f16x8*>(lds + sl * SLAB_BYTES + chunk * 16) = v;
    }

    // ---- wf: coalesced gather + LDS scatter (72 entries/thread) ----
    {
        const float2* filts2 = reinterpret_cast<const float2*>(filts);
        _Float16* wfh = reinterpret_cast<_Float16*>(wfl);
        #pragma unroll
        for (int k = 0; k < 72; ++k) {
            const int f = tid + k * 512;         // entry = i*576 + o*9 + t
            const float v = filts2[f].x;         // real plane
            const int i   = f / 576;
            const int rem = f - i * 576;
            const int o   = rem / 9;
            const int t   = rem - o * 9;
            const int kc = i >> 5, hh = (i >> 3) & 3, e = i & 7;
            const int n  = o >> 4,  rr = o & 15;
            const int c  = ((t * 2 + kc) * 4 + n) * 64 + hh * 16 + rr;
            wfh[c * 8 + e] = (_Float16)v;
        }
    }
    __syncthreads();

    const int row = w >> 1;              // output row within quad (0..3)
    const int xh  = w & 1;               // x half (0..1)

    f32x4 acc[2][4];
    #pragma unroll
    for (int m = 0; m < 2; ++m)
        #pragma unroll
        for (int n = 0; n < 4; ++n)
            acc[m][n] = f32x4{0.f, 0.f, 0.f, 0.f};

    #pragma unroll
    for (int ky = 0; ky < 3; ++ky) {
        const char* slab = lds + (row + 2 - ky) * SLAB_BYTES;   // sl in 0..5
        #pragma unroll
        for (int kx = 0; kx < 3; ++kx) {
            const int t = ky * 3 + kx;
            const char* wt = wfl + (size_t)t * 8192;   // 512 chunks * 16B per tap
            #pragma unroll
            for (int kc = 0; kc < 2; ++kc) {
                f16x8 a[2], bb[4];
                #pragma unroll
                for (int m = 0; m < 2; ++m) {
                    const int xp = xh * 32 + m * 16 + r + 2 - kx;  // 0..65
                    const int chunk = xp * 8 + (((kc << 2) + h) ^ (xp & 7));
                    a[m] = *reinterpret_cast<const f16x8*>(slab + chunk * 16);
                }
                #pragma unroll
                for (int n = 0; n < 4; ++n)
                    bb[n] = *reinterpret_cast<const f16x8*>(
                        wt + (size_t)(kc * 4 + n) * 1024 + l * 16);
                #pragma unroll
                for (int m = 0; m < 2; ++m)
                    #pragma unroll
                    for (int n = 0; n < 4; ++n)
                        acc[m][n] = __builtin_amdgcn_mfma_f32_16x16x32_f16(a[m], bb[n], acc[m][n], 0, 0, 0);
            }
        }
    }

    const int y = y0 + row;
    #pragma unroll
    for (int m = 0; m < 2; ++m) {
        const int x0 = xh * 32 + m * 16 + h * 4;
        #pragma unroll
        for (int n = 0; n < 4; ++n) {
            const int o = n * 16 + r;
            *reinterpret_cast<f32x4*>(out + (((size_t)(b * 64 + o) * 64 + y) * 64) + x0) = acc[m][n];
        }
    }
}

extern "C" void kernel_launch(void* const* d_in, const int* in_sizes, int n_in,
                              void* d_out, int out_size, void* d_ws, size_t ws_size,
                              hipStream_t stream) {
    const float* imgs  = (const float*)d_in[0];   // [16][64][64][64] f32
    const float* filts = (const float*)d_in[1];   // [1][64][64][3][3][2] f32
    float* out = (float*)d_out;                   // [16][64][64][64] f32
    (void)d_ws; (void)ws_size;                    // no workspace needed

    hipLaunchKernelGGL(conv_one, dim3(256), dim3(512), 0, stream, imgs, filts, out);
}